// Round 1
// baseline (687.273 us; speedup 1.0000x reference)
//
#include <hip/hip_runtime.h>
#include <hip/hip_bf16.h>

typedef unsigned short u16;
typedef unsigned int u32;

#define N_TOK 4096
#define DIM   1024
#define HID   4096
#define N_EXP 8
#define CAP   1280

typedef short short8 __attribute__((ext_vector_type(8)));
typedef float f32x4 __attribute__((ext_vector_type(4)));

__device__ __forceinline__ u16 bf16rne(float f) {
    u32 u = __float_as_uint(f);
    u32 r = u + 0x7FFFu + ((u >> 16) & 1u);
    return (u16)(r >> 16);
}
__device__ __forceinline__ float bf2f(u16 h) {
    return __uint_as_float(((u32)h) << 16);
}

// ---------------- Router: one wave per token ----------------
__global__ void router_kernel(const float* __restrict__ x,
                              const float* __restrict__ gw,
                              int* __restrict__ r_eidx,
                              float* __restrict__ r_w) {
    const int wave = threadIdx.x >> 6, lane = threadIdx.x & 63;
    const int t = blockIdx.x * 4 + wave;
    const float* xr = x + (size_t)t * DIM;
    float acc[8];
#pragma unroll
    for (int e = 0; e < 8; e++) acc[e] = 0.f;
#pragma unroll 4
    for (int i = 0; i < DIM / 64; i++) {
        int d = i * 64 + lane;
        float xv = xr[d];
        const float4* g = (const float4*)(gw + (size_t)d * 8);
        float4 g0 = g[0], g1 = g[1];
        acc[0] += xv * g0.x; acc[1] += xv * g0.y;
        acc[2] += xv * g0.z; acc[3] += xv * g0.w;
        acc[4] += xv * g1.x; acc[5] += xv * g1.y;
        acc[6] += xv * g1.z; acc[7] += xv * g1.w;
    }
#pragma unroll
    for (int e = 0; e < 8; e++) {
#pragma unroll
        for (int off = 32; off > 0; off >>= 1)
            acc[e] += __shfl_xor(acc[e], off, 64);
    }
    if (lane == 0) {
        int e0 = 0; float l0 = acc[0];
#pragma unroll
        for (int e = 1; e < 8; e++) if (acc[e] > l0) { l0 = acc[e]; e0 = e; }
        int e1 = -1; float l1 = -1e30f;
#pragma unroll
        for (int e = 0; e < 8; e++) if (e != e0 && acc[e] > l1) { l1 = acc[e]; e1 = e; }
        float z = __expf(l1 - l0);          // <= 1
        float inv = 1.f / (1.f + z);
        r_eidx[t] = e0; r_eidx[N_TOK + t] = e1;
        r_w[t] = inv;   r_w[N_TOK + t] = z * inv;
    }
}

// ---------------- Capacity assignment: single block, deterministic scan ------
__global__ void assign_kernel(const int* __restrict__ r_eidx,
                              int* __restrict__ assign_slot,
                              int* __restrict__ token_for_slot) {
    const int tid = threadIdx.x;                 // 0..1023
    __shared__ int wtot[8][16];
    __shared__ int wbase[8][16];
    for (int i = tid; i < N_EXP * CAP; i += 1024) token_for_slot[i] = -1;

    // each thread owns 8 consecutive entries (k-major order: i = k*4096 + t)
    int le[8], lr[8], cnt[8];
#pragma unroll
    for (int e = 0; e < 8; e++) cnt[e] = 0;
#pragma unroll
    for (int j = 0; j < 8; j++) {
        int e = r_eidx[tid * 8 + j];
        le[j] = e;
        int r = 0;
#pragma unroll
        for (int e2 = 0; e2 < 8; e2++)
            if (e == e2) { r = cnt[e2]; cnt[e2] = r + 1; }
        lr[j] = r;
    }
    const int lane = tid & 63, wv = tid >> 6;    // 16 waves
    int excl[8];
#pragma unroll
    for (int e = 0; e < 8; e++) {
        int v = cnt[e], inc = v;
#pragma unroll
        for (int off = 1; off < 64; off <<= 1) {
            int u = __shfl_up(inc, off, 64);
            if (lane >= off) inc += u;
        }
        excl[e] = inc - v;
        if (lane == 63) wtot[e][wv] = inc;
    }
    __syncthreads();
    if (tid < 8) {
        int s = 0;
        for (int w = 0; w < 16; w++) { wbase[tid][w] = s; s += wtot[tid][w]; }
    }
    __syncthreads();
#pragma unroll
    for (int j = 0; j < 8; j++) {
        int i = tid * 8 + j;
        int e = le[j];
        int b = 0;
#pragma unroll
        for (int e2 = 0; e2 < 8; e2++)
            if (e == e2) b = wbase[e2][wv] + excl[e2];
        int rank = b + lr[j];
        int tok = i & (N_TOK - 1);
        if (rank < CAP) {
            assign_slot[i] = rank;
            token_for_slot[e * CAP + rank] = tok;
        } else {
            assign_slot[i] = -1;
        }
    }
}

// ---------------- Gather tokens into per-expert batches (bf16) ----------------
__global__ void gather_kernel(const float* __restrict__ x,
                              const int* __restrict__ token_for_slot,
                              u16* __restrict__ exp_batches) {
    const int s = blockIdx.x;
    const int tok = token_for_slot[s];
    const int d = threadIdx.x * 4;
    ushort4 o;
    if (tok >= 0) {
        float4 v = *(const float4*)(x + (size_t)tok * DIM + d);
        o = make_ushort4(bf16rne(v.x), bf16rne(v.y), bf16rne(v.z), bf16rne(v.w));
    } else {
        o = make_ushort4(0, 0, 0, 0);
    }
    *(ushort4*)(exp_batches + (size_t)s * DIM + d) = o;
}

// ---------------- MFMA GEMM: C(bf16) = epi(A(bf16) @ B(f32) + bias) ----------
// A: [M,K] bf16 row-major.  B: [K,N] f32 row-major (transposed+cvt in staging).
#define BM 128
#define BN 128
#define BKT 64
#define LDT 72   // padded LDS row stride (elements); 144 B, 16B-aligned

template <bool DO_GELU>
__global__ __launch_bounds__(256, 2) void moe_gemm(
    const u16* __restrict__ A, const float* __restrict__ Bw,
    const float* __restrict__ bias, u16* __restrict__ C,
    int M, int N, int K) {
    __shared__ __align__(16) u16 As[BM * LDT];
    __shared__ __align__(16) u16 Bs[BN * LDT];

    const int e = blockIdx.z;
    A    += (size_t)e * M * K;
    Bw   += (size_t)e * K * N;
    bias += (size_t)e * N;
    C    += (size_t)e * M * N;

    const int tid = threadIdx.x;
    const int lane = tid & 63, wave = tid >> 6;
    const int wr = (wave >> 1) * 64, wc = (wave & 1) * 64;
    const int row0 = blockIdx.y * BM, col0 = blockIdx.x * BN;

    f32x4 acc[4][4];
#pragma unroll
    for (int i = 0; i < 4; i++)
#pragma unroll
        for (int j = 0; j < 4; j++) acc[i][j] = (f32x4){0.f, 0.f, 0.f, 0.f};

    const int ar = tid >> 1, ah = (tid & 1) * 32;      // A staging: row, k-half
    const int bkg = tid >> 5, bng = (tid & 31) * 4;    // B staging: k-grp, n

    for (int kt = 0; kt < K; kt += BKT) {
        // ---- stage A (bf16, direct copy) ----
        const u16* Ag = A + (size_t)(row0 + ar) * K + kt + ah;
#pragma unroll
        for (int c = 0; c < 4; c++) {
            uint4 v = *(const uint4*)(Ag + c * 8);
            *(uint4*)(As + ar * LDT + ah + c * 8) = v;
        }
        // ---- stage B (f32 -> bf16, transpose into Bs[n][k]) ----
#pragma unroll
        for (int p = 0; p < 2; p++) {
            int g = bkg + p * 8;                        // k-group 0..15
            const float* Bg = Bw + (size_t)(kt + g * 4) * N + col0 + bng;
            float4 f0 = *(const float4*)(Bg);
            float4 f1 = *(const float4*)(Bg + N);
            float4 f2 = *(const float4*)(Bg + 2 * (size_t)N);
            float4 f3 = *(const float4*)(Bg + 3 * (size_t)N);
            const float* q0 = (const float*)&f0;
            const float* q1 = (const float*)&f1;
            const float* q2 = (const float*)&f2;
            const float* q3 = (const float*)&f3;
#pragma unroll
            for (int j = 0; j < 4; j++) {
                u32 lo = (u32)bf16rne(q0[j]) | ((u32)bf16rne(q1[j]) << 16);
                u32 hi = (u32)bf16rne(q2[j]) | ((u32)bf16rne(q3[j]) << 16);
                uint2 w2; w2.x = lo; w2.y = hi;
                *(uint2*)(Bs + (bng + j) * LDT + g * 4) = w2;
            }
        }
        __syncthreads();
        // ---- compute: 2 k-steps of 32 ----
#pragma unroll
        for (int ks = 0; ks < 2; ks++) {
            const int krd = ks * 32 + (lane >> 4) * 8;
            const int rrd = lane & 15;
            short8 af[4], bfr[4];
#pragma unroll
            for (int i = 0; i < 4; i++)
                af[i] = *(const short8*)(As + (wr + i * 16 + rrd) * LDT + krd);
#pragma unroll
            for (int j = 0; j < 4; j++)
                bfr[j] = *(const short8*)(Bs + (wc + j * 16 + rrd) * LDT + krd);
#pragma unroll
            for (int i = 0; i < 4; i++)
#pragma unroll
                for (int j = 0; j < 4; j++)
                    acc[i][j] = __builtin_amdgcn_mfma_f32_16x16x32_bf16(
                        af[i], bfr[j], acc[i][j], 0, 0, 0);
        }
        __syncthreads();
    }
    // ---- epilogue: bias (+gelu) -> bf16 ----
    const int cr = (lane >> 4) * 4;
    const int cc = lane & 15;
#pragma unroll
    for (int j = 0; j < 4; j++) {
        const int col = col0 + wc + j * 16 + cc;
        const float bv = bias[col];
#pragma unroll
        for (int i = 0; i < 4; i++) {
#pragma unroll
            for (int r = 0; r < 4; r++) {
                int row = row0 + wr + i * 16 + cr + r;
                float v = acc[i][j][r] + bv;
                if (DO_GELU) v = 0.5f * v * (1.0f + erff(v * 0.70710678118f));
                C[(size_t)row * N + col] = bf16rne(v);
            }
        }
    }
}

// ---------------- Combine: out = w0*expOut[e0,s0] + w1*expOut[e1,s1] ----------
__global__ void combine_kernel(const int* __restrict__ r_eidx,
                               const float* __restrict__ r_w,
                               const int* __restrict__ assign_slot,
                               const u16* __restrict__ exp_out,
                               float* __restrict__ out) {
    const int t = blockIdx.x;
    const int d = threadIdx.x * 4;
    const int e0 = r_eidx[t], e1 = r_eidx[N_TOK + t];
    const float w0 = r_w[t], w1 = r_w[N_TOK + t];
    const int s0 = assign_slot[t], s1 = assign_slot[N_TOK + t];
    float v0 = 0.f, v1 = 0.f, v2 = 0.f, v3 = 0.f;
    if (s0 >= 0) {
        const u16* p = exp_out + ((size_t)e0 * CAP + s0) * DIM + d;
        ushort4 q = *(const ushort4*)p;
        v0 += w0 * bf2f(q.x); v1 += w0 * bf2f(q.y);
        v2 += w0 * bf2f(q.z); v3 += w0 * bf2f(q.w);
    }
    if (s1 >= 0) {
        const u16* p = exp_out + ((size_t)e1 * CAP + s1) * DIM + d;
        ushort4 q = *(const ushort4*)p;
        v0 += w1 * bf2f(q.x); v1 += w1 * bf2f(q.y);
        v2 += w1 * bf2f(q.z); v3 += w1 * bf2f(q.w);
    }
    float4 o; o.x = v0; o.y = v1; o.z = v2; o.w = v3;
    *(float4*)(out + (size_t)t * DIM + d) = o;
}

// ---------------- Launch ----------------
extern "C" void kernel_launch(void* const* d_in, const int* in_sizes, int n_in,
                              void* d_out, int out_size, void* d_ws, size_t ws_size,
                              hipStream_t stream) {
    const float* x         = (const float*)d_in[0];
    const float* gate_w    = (const float*)d_in[1];
    const float* c_fc      = (const float*)d_in[2];
    const float* fc_bias   = (const float*)d_in[3];
    const float* c_proj    = (const float*)d_in[4];
    const float* proj_bias = (const float*)d_in[5];
    float* out = (float*)d_out;
    char* ws = (char*)d_ws;

    // workspace layout (bytes)
    int*   r_eidx         = (int*)(ws + 0);              //  32 KB (2*4096 int)
    float* r_w            = (float*)(ws + 32768);        //  32 KB
    int*   assign_slot    = (int*)(ws + 65536);          //  32 KB
    int*   token_for_slot = (int*)(ws + 98304);          //  40 KB (10240 int)
    u16*   exp_batches    = (u16*)(ws + 139264);         //  20.97 MB [10240,1024]
    u16*   h              = (u16*)(ws + 21110784);       //  83.9  MB [10240,4096]
    u16*   exp_out        = (u16*)(ws + 104996864);      //  20.97 MB [10240,1024]
    // total: 125,968,384 bytes

    router_kernel<<<N_TOK / 4, 256, 0, stream>>>(x, gate_w, r_eidx, r_w);
    assign_kernel<<<1, 1024, 0, stream>>>(r_eidx, assign_slot, token_for_slot);
    gather_kernel<<<N_EXP * CAP, 256, 0, stream>>>(x, token_for_slot, exp_batches);
    moe_gemm<true><<<dim3(HID / BN, CAP / BM, N_EXP), 256, 0, stream>>>(
        exp_batches, c_fc, fc_bias, h, CAP, HID, DIM);
    moe_gemm<false><<<dim3(DIM / BN, CAP / BM, N_EXP), 256, 0, stream>>>(
        h, c_proj, proj_bias, exp_out, CAP, DIM, HID);
    combine_kernel<<<N_TOK, 256, 0, stream>>>(r_eidx, r_w, assign_slot, exp_out, out);
}

// Round 2
// 584.334 us; speedup vs baseline: 1.1762x; 1.1762x over previous
//
#include <hip/hip_runtime.h>
#include <hip/hip_bf16.h>

typedef unsigned short u16;
typedef unsigned int u32;

#define N_TOK 4096
#define DIM   1024
#define HID   4096
#define N_EXP 8
#define CAP   1280

typedef short short8 __attribute__((ext_vector_type(8)));
typedef float f32x4 __attribute__((ext_vector_type(4)));

__device__ __forceinline__ u16 bf16rne(float f) {
    u32 u = __float_as_uint(f);
    u32 r = u + 0x7FFFu + ((u >> 16) & 1u);
    return (u16)(r >> 16);
}
__device__ __forceinline__ float bf2f(u16 h) {
    return __uint_as_float(((u32)h) << 16);
}

#define GLDS(gp, lp) __builtin_amdgcn_global_load_lds( \
    (const __attribute__((address_space(1))) void*)(gp), \
    (__attribute__((address_space(3))) void*)(lp), 16, 0, 0)

// ---------------- Router: one wave per token ----------------
__global__ void router_kernel(const float* __restrict__ x,
                              const float* __restrict__ gw,
                              int* __restrict__ r_eidx,
                              float* __restrict__ r_w) {
    const int wave = threadIdx.x >> 6, lane = threadIdx.x & 63;
    const int t = blockIdx.x * 4 + wave;
    const float* xr = x + (size_t)t * DIM;
    float acc[8];
#pragma unroll
    for (int e = 0; e < 8; e++) acc[e] = 0.f;
#pragma unroll 4
    for (int i = 0; i < DIM / 64; i++) {
        int d = i * 64 + lane;
        float xv = xr[d];
        const float4* g = (const float4*)(gw + (size_t)d * 8);
        float4 g0 = g[0], g1 = g[1];
        acc[0] += xv * g0.x; acc[1] += xv * g0.y;
        acc[2] += xv * g0.z; acc[3] += xv * g0.w;
        acc[4] += xv * g1.x; acc[5] += xv * g1.y;
        acc[6] += xv * g1.z; acc[7] += xv * g1.w;
    }
#pragma unroll
    for (int e = 0; e < 8; e++) {
#pragma unroll
        for (int off = 32; off > 0; off >>= 1)
            acc[e] += __shfl_xor(acc[e], off, 64);
    }
    if (lane == 0) {
        int e0 = 0; float l0 = acc[0];
#pragma unroll
        for (int e = 1; e < 8; e++) if (acc[e] > l0) { l0 = acc[e]; e0 = e; }
        int e1 = -1; float l1 = -1e30f;
#pragma unroll
        for (int e = 0; e < 8; e++) if (e != e0 && acc[e] > l1) { l1 = acc[e]; e1 = e; }
        float z = __expf(l1 - l0);          // <= 1
        float inv = 1.f / (1.f + z);
        r_eidx[t] = e0; r_eidx[N_TOK + t] = e1;
        r_w[t] = inv;   r_w[N_TOK + t] = z * inv;
    }
}

// ---------------- Capacity assignment: single block, deterministic scan ------
__global__ void assign_kernel(const int* __restrict__ r_eidx,
                              int* __restrict__ assign_slot,
                              int* __restrict__ token_for_slot) {
    const int tid = threadIdx.x;                 // 0..1023
    __shared__ int wtot[8][16];
    __shared__ int wbase[8][16];
    for (int i = tid; i < N_EXP * CAP; i += 1024) token_for_slot[i] = -1;

    int le[8], lr[8], cnt[8];
#pragma unroll
    for (int e = 0; e < 8; e++) cnt[e] = 0;
#pragma unroll
    for (int j = 0; j < 8; j++) {
        int e = r_eidx[tid * 8 + j];
        le[j] = e;
        int r = 0;
#pragma unroll
        for (int e2 = 0; e2 < 8; e2++)
            if (e == e2) { r = cnt[e2]; cnt[e2] = r + 1; }
        lr[j] = r;
    }
    const int lane = tid & 63, wv = tid >> 6;    // 16 waves
    int excl[8];
#pragma unroll
    for (int e = 0; e < 8; e++) {
        int v = cnt[e], inc = v;
#pragma unroll
        for (int off = 1; off < 64; off <<= 1) {
            int u = __shfl_up(inc, off, 64);
            if (lane >= off) inc += u;
        }
        excl[e] = inc - v;
        if (lane == 63) wtot[e][wv] = inc;
    }
    __syncthreads();
    if (tid < 8) {
        int s = 0;
        for (int w = 0; w < 16; w++) { wbase[tid][w] = s; s += wtot[tid][w]; }
    }
    __syncthreads();
#pragma unroll
    for (int j = 0; j < 8; j++) {
        int i = tid * 8 + j;
        int e = le[j];
        int b = 0;
#pragma unroll
        for (int e2 = 0; e2 < 8; e2++)
            if (e == e2) b = wbase[e2][wv] + excl[e2];
        int rank = b + lr[j];
        int tok = i & (N_TOK - 1);
        if (rank < CAP) {
            assign_slot[i] = rank;
            token_for_slot[e * CAP + rank] = tok;
        } else {
            assign_slot[i] = -1;
        }
    }
}

// ---------------- Gather tokens into per-expert batches (bf16) ----------------
__global__ void gather_kernel(const float* __restrict__ x,
                              const int* __restrict__ token_for_slot,
                              u16* __restrict__ exp_batches) {
    const int s = blockIdx.x;
    const int tok = token_for_slot[s];
    const int d = threadIdx.x * 4;
    ushort4 o;
    if (tok >= 0) {
        float4 v = *(const float4*)(x + (size_t)tok * DIM + d);
        o = make_ushort4(bf16rne(v.x), bf16rne(v.y), bf16rne(v.z), bf16rne(v.w));
    } else {
        o = make_ushort4(0, 0, 0, 0);
    }
    *(ushort4*)(exp_batches + (size_t)s * DIM + d) = o;
}

// ---------------- Weight transpose+convert: f32 [R][C] -> bf16 [C][R] --------
// 64x64 tiles, conflict-free LDS (f32 tile, 65-elem stride; 2-way max = free).
__global__ __launch_bounds__(256) void transpose_cvt(
    const float* __restrict__ in, u16* __restrict__ out, int R, int C) {
    __shared__ float t[64][65];
    const int ez = blockIdx.z;
    in  += (size_t)ez * R * C;
    out += (size_t)ez * R * C;
    const int row0 = blockIdx.y * 64, col0 = blockIdx.x * 64;
    const int tid = threadIdx.x;
    {
        const int r = tid >> 2, cq = (tid & 3) * 16;
        const float* p = in + (size_t)(row0 + r) * C + col0 + cq;
        float4 v0 = ((const float4*)p)[0];
        float4 v1 = ((const float4*)p)[1];
        float4 v2 = ((const float4*)p)[2];
        float4 v3 = ((const float4*)p)[3];
        float tmp[16] = {v0.x, v0.y, v0.z, v0.w, v1.x, v1.y, v1.z, v1.w,
                         v2.x, v2.y, v2.z, v2.w, v3.x, v3.y, v3.z, v3.w};
#pragma unroll
        for (int j = 0; j < 16; j++) t[r][cq + j] = tmp[j];
    }
    __syncthreads();
    {
        const int oc = tid >> 2, h4 = (tid & 3) * 16;
        u16 o[16];
#pragma unroll
        for (int i = 0; i < 16; i++) o[i] = bf16rne(t[h4 + i][oc]);
        u16* q = out + (size_t)(col0 + oc) * R + row0 + h4;
        *(uint4*)q = *(const uint4*)&o[0];
        *(uint4*)(q + 8) = *(const uint4*)&o[8];
    }
}

// ---------------- MFMA GEMM (m97 structure): C = epi(A @ Bt^T + bias) --------
// A: [M,K] bf16 row-major.  Bt: [N,K] bf16 row-major (pre-transposed weights).
// LDS [128][64] bf16 unpadded; k-chunk XOR-swizzled by row&7 (applied in the
// global address so global_load_lds stays contiguous; permutation is within
// one 128B row so global coalescing is unchanged).
template <bool DO_GELU>
__global__ __launch_bounds__(256, 2) void moe_gemm(
    const u16* __restrict__ A, const u16* __restrict__ Bt,
    const float* __restrict__ bias, u16* __restrict__ C,
    int M, int N, int K) {
    __shared__ __align__(16) u16 As[128 * 64];
    __shared__ __align__(16) u16 Bs[128 * 64];

    const int e = blockIdx.z;
    A    += (size_t)e * M * K;
    Bt   += (size_t)e * N * K;
    bias += (size_t)e * N;
    C    += (size_t)e * M * N;

    const int tid = threadIdx.x;
    const int lane = tid & 63, wave = tid >> 6;
    const int wr = (wave >> 1) * 64, wc = (wave & 1) * 64;
    const int row0 = blockIdx.y * 128, col0 = blockIdx.x * 128;

    f32x4 acc[4][4];
#pragma unroll
    for (int i = 0; i < 4; i++)
#pragma unroll
        for (int j = 0; j < 4; j++) acc[i][j] = (f32x4){0.f, 0.f, 0.f, 0.f};

    // staging: chunk = wave*4+i covers LDS bytes chunk*1024 + lane*16
    //          = rows chunk*8 + (lane>>3), k-chunk (lane&7) (16B of k)
    const int srow = lane >> 3;
    const int swz = ((lane & 7) ^ srow) * 8;     // XOR k-swizzle by row&7
    const u16* Ab = A + (size_t)(row0 + wave * 32 + srow) * K + swz;
    const u16* Bb = Bt + (size_t)(col0 + wave * 32 + srow) * K + swz;
    u16* Asw = As + (wave * 4) * 512;
    u16* Bsw = Bs + (wave * 4) * 512;

    const int rrd = lane & 15, qrd = lane >> 4;
    const int sw = rrd & 7;                       // frag-read swizzle key

    for (int kt = 0; kt < K; kt += 64) {
#pragma unroll
        for (int i = 0; i < 4; i++)
            GLDS(Ab + (size_t)(i * 8) * K + kt, Asw + i * 512);
#pragma unroll
        for (int i = 0; i < 4; i++)
            GLDS(Bb + (size_t)(i * 8) * K + kt, Bsw + i * 512);
        __syncthreads();
#pragma unroll
        for (int ks = 0; ks < 2; ks++) {
            const int kc = ks * 4 + qrd;          // logical k-chunk 0..7
            const int krd = (kc ^ sw) * 8;        // swizzled element offset
            short8 af[4], bfr[4];
#pragma unroll
            for (int i = 0; i < 4; i++)
                af[i] = *(const short8*)(As + (wr + i * 16 + rrd) * 64 + krd);
#pragma unroll
            for (int j = 0; j < 4; j++)
                bfr[j] = *(const short8*)(Bs + (wc + j * 16 + rrd) * 64 + krd);
#pragma unroll
            for (int i = 0; i < 4; i++)
#pragma unroll
                for (int j = 0; j < 4; j++)
                    acc[i][j] = __builtin_amdgcn_mfma_f32_16x16x32_bf16(
                        af[i], bfr[j], acc[i][j], 0, 0, 0);
        }
        __syncthreads();
    }
    // ---- epilogue: bias (+gelu) -> bf16 ----
    const int cr = (lane >> 4) * 4;
    const int cc = lane & 15;
#pragma unroll
    for (int j = 0; j < 4; j++) {
        const int col = col0 + wc + j * 16 + cc;
        const float bv = bias[col];
#pragma unroll
        for (int i = 0; i < 4; i++) {
#pragma unroll
            for (int r = 0; r < 4; r++) {
                int row = row0 + wr + i * 16 + cr + r;
                float v = acc[i][j][r] + bv;
                if (DO_GELU) v = 0.5f * v * (1.0f + erff(v * 0.70710678118f));
                C[(size_t)row * N + col] = bf16rne(v);
            }
        }
    }
}

// ---------------- Combine: out = w0*expOut[e0,s0] + w1*expOut[e1,s1] ----------
__global__ void combine_kernel(const int* __restrict__ r_eidx,
                               const float* __restrict__ r_w,
                               const int* __restrict__ assign_slot,
                               const u16* __restrict__ exp_out,
                               float* __restrict__ out) {
    const int t = blockIdx.x;
    const int d = threadIdx.x * 4;
    const int e0 = r_eidx[t], e1 = r_eidx[N_TOK + t];
    const float w0 = r_w[t], w1 = r_w[N_TOK + t];
    const int s0 = assign_slot[t], s1 = assign_slot[N_TOK + t];
    float v0 = 0.f, v1 = 0.f, v2 = 0.f, v3 = 0.f;
    if (s0 >= 0) {
        const u16* p = exp_out + ((size_t)e0 * CAP + s0) * DIM + d;
        ushort4 q = *(const ushort4*)p;
        v0 += w0 * bf2f(q.x); v1 += w0 * bf2f(q.y);
        v2 += w0 * bf2f(q.z); v3 += w0 * bf2f(q.w);
    }
    if (s1 >= 0) {
        const u16* p = exp_out + ((size_t)e1 * CAP + s1) * DIM + d;
        ushort4 q = *(const ushort4*)p;
        v0 += w1 * bf2f(q.x); v1 += w1 * bf2f(q.y);
        v2 += w1 * bf2f(q.z); v3 += w1 * bf2f(q.w);
    }
    float4 o; o.x = v0; o.y = v1; o.z = v2; o.w = v3;
    *(float4*)(out + (size_t)t * DIM + d) = o;
}

// ---------------- Launch ----------------
extern "C" void kernel_launch(void* const* d_in, const int* in_sizes, int n_in,
                              void* d_out, int out_size, void* d_ws, size_t ws_size,
                              hipStream_t stream) {
    const float* x         = (const float*)d_in[0];
    const float* gate_w    = (const float*)d_in[1];
    const float* c_fc      = (const float*)d_in[2];
    const float* fc_bias   = (const float*)d_in[3];
    const float* c_proj    = (const float*)d_in[4];
    const float* proj_bias = (const float*)d_in[5];
    float* out = (float*)d_out;
    char* ws = (char*)d_ws;

    // workspace layout (bytes)
    int*   r_eidx         = (int*)(ws + 0);              //  32 KB
    float* r_w            = (float*)(ws + 32768);        //  32 KB
    int*   assign_slot    = (int*)(ws + 65536);          //  32 KB
    int*   token_for_slot = (int*)(ws + 98304);          //  40 KB (pad to 64)
    u16*   exp_batches    = (u16*)(ws + 163840);         //  20.97 MB [10240,1024]
    u16*   h              = (u16*)(ws + 21135360);       //  83.9  MB [10240,4096]
    u16*   exp_out        = (u16*)(ws + 105021440);      //  20.97 MB [10240,1024]
    u16*   Bt             = (u16*)(ws + 125992960);      //  64 MB (Bt1 then Bt2)
    // total: 193,101,824 bytes (~184 MB)

    router_kernel<<<N_TOK / 4, 256, 0, stream>>>(x, gate_w, r_eidx, r_w);
    assign_kernel<<<1, 1024, 0, stream>>>(r_eidx, assign_slot, token_for_slot);
    gather_kernel<<<N_EXP * CAP, 256, 0, stream>>>(x, token_for_slot, exp_batches);

    // Bt1 = c_fc^T per expert: [D,H] -> [H,D]
    transpose_cvt<<<dim3(HID / 64, DIM / 64, N_EXP), 256, 0, stream>>>(
        c_fc, Bt, DIM, HID);
    moe_gemm<true><<<dim3(HID / 128, CAP / 128, N_EXP), 256, 0, stream>>>(
        exp_batches, Bt, fc_bias, h, CAP, HID, DIM);

    // Bt2 = c_proj^T per expert: [H,D] -> [D,H]  (aliases Bt1, now dead)
    transpose_cvt<<<dim3(DIM / 64, HID / 64, N_EXP), 256, 0, stream>>>(
        c_proj, Bt, HID, DIM);
    moe_gemm<false><<<dim3(DIM / 128, CAP / 128, N_EXP), 256, 0, stream>>>(
        h, Bt, proj_bias, exp_out, CAP, DIM, HID);

    combine_kernel<<<N_TOK, 256, 0, stream>>>(r_eidx, r_w, assign_slot, exp_out, out);
}

// Round 3
// 580.944 us; speedup vs baseline: 1.1830x; 1.0058x over previous
//
#include <hip/hip_runtime.h>
#include <hip/hip_bf16.h>

typedef unsigned short u16;
typedef unsigned int u32;

#define N_TOK 4096
#define DIM   1024
#define HID   4096
#define N_EXP 8
#define CAP   1280

typedef short short8 __attribute__((ext_vector_type(8)));
typedef float f32x16 __attribute__((ext_vector_type(16)));

__device__ __forceinline__ u16 bf16rne(float f) {
    u32 u = __float_as_uint(f);
    u32 r = u + 0x7FFFu + ((u >> 16) & 1u);
    return (u16)(r >> 16);
}
__device__ __forceinline__ float bf2f(u16 h) {
    return __uint_as_float(((u32)h) << 16);
}

#define GLDS(gp, lp) __builtin_amdgcn_global_load_lds( \
    (const __attribute__((address_space(1))) void*)(gp), \
    (__attribute__((address_space(3))) void*)(lp), 16, 0, 0)

// ---------------- Router: one wave per token ----------------
__global__ void router_kernel(const float* __restrict__ x,
                              const float* __restrict__ gw,
                              int* __restrict__ r_eidx,
                              float* __restrict__ r_w) {
    const int wave = threadIdx.x >> 6, lane = threadIdx.x & 63;
    const int t = blockIdx.x * 4 + wave;
    const float* xr = x + (size_t)t * DIM;
    float acc[8];
#pragma unroll
    for (int e = 0; e < 8; e++) acc[e] = 0.f;
#pragma unroll 4
    for (int i = 0; i < DIM / 64; i++) {
        int d = i * 64 + lane;
        float xv = xr[d];
        const float4* g = (const float4*)(gw + (size_t)d * 8);
        float4 g0 = g[0], g1 = g[1];
        acc[0] += xv * g0.x; acc[1] += xv * g0.y;
        acc[2] += xv * g0.z; acc[3] += xv * g0.w;
        acc[4] += xv * g1.x; acc[5] += xv * g1.y;
        acc[6] += xv * g1.z; acc[7] += xv * g1.w;
    }
#pragma unroll
    for (int e = 0; e < 8; e++) {
#pragma unroll
        for (int off = 32; off > 0; off >>= 1)
            acc[e] += __shfl_xor(acc[e], off, 64);
    }
    if (lane == 0) {
        int e0 = 0; float l0 = acc[0];
#pragma unroll
        for (int e = 1; e < 8; e++) if (acc[e] > l0) { l0 = acc[e]; e0 = e; }
        int e1 = -1; float l1 = -1e30f;
#pragma unroll
        for (int e = 0; e < 8; e++) if (e != e0 && acc[e] > l1) { l1 = acc[e]; e1 = e; }
        float z = __expf(l1 - l0);          // <= 1
        float inv = 1.f / (1.f + z);
        r_eidx[t] = e0; r_eidx[N_TOK + t] = e1;
        r_w[t] = inv;   r_w[N_TOK + t] = z * inv;
    }
}

// ---------------- Capacity assignment: single block, deterministic scan ------
__global__ void assign_kernel(const int* __restrict__ r_eidx,
                              int* __restrict__ assign_slot,
                              int* __restrict__ token_for_slot) {
    const int tid = threadIdx.x;                 // 0..1023
    __shared__ int wtot[8][16];
    __shared__ int wbase[8][16];
    for (int i = tid; i < N_EXP * CAP; i += 1024) token_for_slot[i] = -1;

    int le[8], lr[8], cnt[8];
#pragma unroll
    for (int e = 0; e < 8; e++) cnt[e] = 0;
#pragma unroll
    for (int j = 0; j < 8; j++) {
        int e = r_eidx[tid * 8 + j];
        le[j] = e;
        int r = 0;
#pragma unroll
        for (int e2 = 0; e2 < 8; e2++)
            if (e == e2) { r = cnt[e2]; cnt[e2] = r + 1; }
        lr[j] = r;
    }
    const int lane = tid & 63, wv = tid >> 6;    // 16 waves
    int excl[8];
#pragma unroll
    for (int e = 0; e < 8; e++) {
        int v = cnt[e], inc = v;
#pragma unroll
        for (int off = 1; off < 64; off <<= 1) {
            int u = __shfl_up(inc, off, 64);
            if (lane >= off) inc += u;
        }
        excl[e] = inc - v;
        if (lane == 63) wtot[e][wv] = inc;
    }
    __syncthreads();
    if (tid < 8) {
        int s = 0;
        for (int w = 0; w < 16; w++) { wbase[tid][w] = s; s += wtot[tid][w]; }
    }
    __syncthreads();
#pragma unroll
    for (int j = 0; j < 8; j++) {
        int i = tid * 8 + j;
        int e = le[j];
        int b = 0;
#pragma unroll
        for (int e2 = 0; e2 < 8; e2++)
            if (e == e2) b = wbase[e2][wv] + excl[e2];
        int rank = b + lr[j];
        int tok = i & (N_TOK - 1);
        if (rank < CAP) {
            assign_slot[i] = rank;
            token_for_slot[e * CAP + rank] = tok;
        } else {
            assign_slot[i] = -1;
        }
    }
}

// ---------------- Gather tokens into per-expert batches (bf16) ----------------
__global__ void gather_kernel(const float* __restrict__ x,
                              const int* __restrict__ token_for_slot,
                              u16* __restrict__ exp_batches) {
    const int s = blockIdx.x;
    const int tok = token_for_slot[s];
    const int d = threadIdx.x * 4;
    ushort4 o;
    if (tok >= 0) {
        float4 v = *(const float4*)(x + (size_t)tok * DIM + d);
        o = make_ushort4(bf16rne(v.x), bf16rne(v.y), bf16rne(v.z), bf16rne(v.w));
    } else {
        o = make_ushort4(0, 0, 0, 0);
    }
    *(ushort4*)(exp_batches + (size_t)s * DIM + d) = o;
}

// ---------------- Weight transpose+convert: f32 [R][C] -> bf16 [C][R] --------
__global__ __launch_bounds__(256) void transpose_cvt(
    const float* __restrict__ in, u16* __restrict__ out, int R, int C) {
    __shared__ float t[64][65];
    const int ez = blockIdx.z;
    in  += (size_t)ez * R * C;
    out += (size_t)ez * R * C;
    const int row0 = blockIdx.y * 64, col0 = blockIdx.x * 64;
    const int tid = threadIdx.x;
    {
        const int r = tid >> 2, cq = (tid & 3) * 16;
        const float* p = in + (size_t)(row0 + r) * C + col0 + cq;
        float4 v0 = ((const float4*)p)[0];
        float4 v1 = ((const float4*)p)[1];
        float4 v2 = ((const float4*)p)[2];
        float4 v3 = ((const float4*)p)[3];
        float tmp[16] = {v0.x, v0.y, v0.z, v0.w, v1.x, v1.y, v1.z, v1.w,
                         v2.x, v2.y, v2.z, v2.w, v3.x, v3.y, v3.z, v3.w};
#pragma unroll
        for (int j = 0; j < 16; j++) t[r][cq + j] = tmp[j];
    }
    __syncthreads();
    {
        const int oc = tid >> 2, h4 = (tid & 3) * 16;
        u16 o[16];
#pragma unroll
        for (int i = 0; i < 16; i++) o[i] = bf16rne(t[h4 + i][oc]);
        u16* q = out + (size_t)(col0 + oc) * R + row0 + h4;
        *(uint4*)q = *(const uint4*)&o[0];
        *(uint4*)(q + 8) = *(const uint4*)&o[8];
    }
}

// ---------------- MFMA GEMM (32x32x16): C = epi(A @ Bt^T + bias) -------------
// A: [M,K] bf16 row-major.  Bt: [N,K] bf16 row-major (pre-transposed weights).
// LDS [128][64] bf16 unpadded; k-chunk XOR-swizzled by row&7 in the GLOBAL
// address (DMA-legal; permutation stays inside one 128B row).
template <bool DO_GELU>
__global__ __launch_bounds__(256, 3) void moe_gemm(
    const u16* __restrict__ A, const u16* __restrict__ Bt,
    const float* __restrict__ bias, u16* __restrict__ C,
    int M, int N, int K) {
    __shared__ __align__(16) u16 As[128 * 64];
    __shared__ __align__(16) u16 Bs[128 * 64];

    const int e = blockIdx.z;
    A    += (size_t)e * M * K;
    Bt   += (size_t)e * N * K;
    bias += (size_t)e * N;
    C    += (size_t)e * M * N;

    const int tid = threadIdx.x;
    const int lane = tid & 63, wave = tid >> 6;
    const int wr = (wave >> 1) * 64, wc = (wave & 1) * 64;
    const int row0 = blockIdx.y * 128, col0 = blockIdx.x * 128;

    f32x16 acc[2][2];
#pragma unroll
    for (int i = 0; i < 2; i++)
#pragma unroll
        for (int j = 0; j < 2; j++)
#pragma unroll
            for (int r = 0; r < 16; r++) acc[i][j][r] = 0.f;

    // staging: chunk = wave*4+i covers LDS bytes chunk*1024 + lane*16
    const int srow = lane >> 3;
    const int swz = ((lane & 7) ^ srow) * 8;     // XOR k-swizzle by row&7
    const u16* Ab = A + (size_t)(row0 + wave * 32 + srow) * K + swz;
    const u16* Bb = Bt + (size_t)(col0 + wave * 32 + srow) * K + swz;
    u16* Asw = As + (wave * 4) * 512;
    u16* Bsw = Bs + (wave * 4) * 512;

    const int ml = lane & 31;                    // m/n within a 32-block
    const int kh = lane >> 5;                    // k-half (0/1)
    const int sw = ml & 7;                       // frag-read swizzle key

    for (int kt = 0; kt < K; kt += 64) {
#pragma unroll
        for (int i = 0; i < 4; i++)
            GLDS(Ab + (size_t)(i * 8) * K + kt, Asw + i * 512);
#pragma unroll
        for (int i = 0; i < 4; i++)
            GLDS(Bb + (size_t)(i * 8) * K + kt, Bsw + i * 512);
        __syncthreads();
#pragma unroll
        for (int ks = 0; ks < 4; ks++) {
            const int kc = ks * 2 + kh;           // logical k-chunk 0..7
            const int krd = (kc ^ sw) * 8;        // swizzled element offset
            short8 af[2], bfr[2];
#pragma unroll
            for (int i = 0; i < 2; i++)
                af[i] = *(const short8*)(As + (wr + i * 32 + ml) * 64 + krd);
#pragma unroll
            for (int j = 0; j < 2; j++)
                bfr[j] = *(const short8*)(Bs + (wc + j * 32 + ml) * 64 + krd);
#pragma unroll
            for (int i = 0; i < 2; i++)
#pragma unroll
                for (int j = 0; j < 2; j++)
                    acc[i][j] = __builtin_amdgcn_mfma_f32_32x32x16_bf16(
                        af[i], bfr[j], acc[i][j], 0, 0, 0);
        }
        __syncthreads();
    }
    // ---- epilogue: bias (+gelu) -> bf16 ----
    // C/D layout: col = lane&31, row = (reg&3) + 8*(reg>>2) + 4*(lane>>5)
    const int rbase = 4 * kh;
#pragma unroll
    for (int j = 0; j < 2; j++) {
        const int col = col0 + wc + j * 32 + ml;
        const float bv = bias[col];
#pragma unroll
        for (int i = 0; i < 2; i++) {
            const int rb = row0 + wr + i * 32 + rbase;
#pragma unroll
            for (int reg = 0; reg < 16; reg++) {
                int row = rb + (reg & 3) + 8 * (reg >> 2);
                float v = acc[i][j][reg] + bv;
                if (DO_GELU) v = 0.5f * v * (1.0f + erff(v * 0.70710678118f));
                C[(size_t)row * N + col] = bf16rne(v);
            }
        }
    }
}

// ---------------- Combine: out = w0*expOut[e0,s0] + w1*expOut[e1,s1] ----------
__global__ void combine_kernel(const int* __restrict__ r_eidx,
                               const float* __restrict__ r_w,
                               const int* __restrict__ assign_slot,
                               const u16* __restrict__ exp_out,
                               float* __restrict__ out) {
    const int t = blockIdx.x;
    const int d = threadIdx.x * 4;
    const int e0 = r_eidx[t], e1 = r_eidx[N_TOK + t];
    const float w0 = r_w[t], w1 = r_w[N_TOK + t];
    const int s0 = assign_slot[t], s1 = assign_slot[N_TOK + t];
    float v0 = 0.f, v1 = 0.f, v2 = 0.f, v3 = 0.f;
    if (s0 >= 0) {
        const u16* p = exp_out + ((size_t)e0 * CAP + s0) * DIM + d;
        ushort4 q = *(const ushort4*)p;
        v0 += w0 * bf2f(q.x); v1 += w0 * bf2f(q.y);
        v2 += w0 * bf2f(q.z); v3 += w0 * bf2f(q.w);
    }
    if (s1 >= 0) {
        const u16* p = exp_out + ((size_t)e1 * CAP + s1) * DIM + d;
        ushort4 q = *(const ushort4*)p;
        v0 += w1 * bf2f(q.x); v1 += w1 * bf2f(q.y);
        v2 += w1 * bf2f(q.z); v3 += w1 * bf2f(q.w);
    }
    float4 o; o.x = v0; o.y = v1; o.z = v2; o.w = v3;
    *(float4*)(out + (size_t)t * DIM + d) = o;
}

// ---------------- Launch ----------------
extern "C" void kernel_launch(void* const* d_in, const int* in_sizes, int n_in,
                              void* d_out, int out_size, void* d_ws, size_t ws_size,
                              hipStream_t stream) {
    const float* x         = (const float*)d_in[0];
    const float* gate_w    = (const float*)d_in[1];
    const float* c_fc      = (const float*)d_in[2];
    const float* fc_bias   = (const float*)d_in[3];
    const float* c_proj    = (const float*)d_in[4];
    const float* proj_bias = (const float*)d_in[5];
    float* out = (float*)d_out;
    char* ws = (char*)d_ws;

    // workspace layout (bytes)
    int*   r_eidx         = (int*)(ws + 0);              //  32 KB
    float* r_w            = (float*)(ws + 32768);        //  32 KB
    int*   assign_slot    = (int*)(ws + 65536);          //  32 KB
    int*   token_for_slot = (int*)(ws + 98304);          //  40 KB (pad to 64)
    u16*   exp_batches    = (u16*)(ws + 163840);         //  20.97 MB [10240,1024]
    u16*   h              = (u16*)(ws + 21135360);       //  83.9  MB [10240,4096]
    u16*   exp_out        = (u16*)(ws + 105021440);      //  20.97 MB [10240,1024]
    u16*   Bt             = (u16*)(ws + 125992960);      //  64 MB (Bt1 then Bt2)
    // total: 193,101,824 bytes (~184 MB)

    router_kernel<<<N_TOK / 4, 256, 0, stream>>>(x, gate_w, r_eidx, r_w);
    assign_kernel<<<1, 1024, 0, stream>>>(r_eidx, assign_slot, token_for_slot);
    gather_kernel<<<N_EXP * CAP, 256, 0, stream>>>(x, token_for_slot, exp_batches);

    // Bt1 = c_fc^T per expert: [D,H] -> [H,D]
    transpose_cvt<<<dim3(HID / 64, DIM / 64, N_EXP), 256, 0, stream>>>(
        c_fc, Bt, DIM, HID);
    moe_gemm<true><<<dim3(HID / 128, CAP / 128, N_EXP), 256, 0, stream>>>(
        exp_batches, Bt, fc_bias, h, CAP, HID, DIM);

    // Bt2 = c_proj^T per expert: [H,D] -> [D,H]  (aliases Bt1, now dead)
    transpose_cvt<<<dim3(DIM / 64, HID / 64, N_EXP), 256, 0, stream>>>(
        c_proj, Bt, HID, DIM);
    moe_gemm<false><<<dim3(DIM / 128, CAP / 128, N_EXP), 256, 0, stream>>>(
        h, Bt, proj_bias, exp_out, CAP, DIM, HID);

    combine_kernel<<<N_TOK, 256, 0, stream>>>(r_eidx, r_w, assign_slot, exp_out, out);
}

// Round 4
// 554.583 us; speedup vs baseline: 1.2393x; 1.0475x over previous
//
#include <hip/hip_runtime.h>
#include <hip/hip_bf16.h>

typedef unsigned short u16;
typedef unsigned int u32;

#define N_TOK 4096
#define DIM   1024
#define HID   4096
#define N_EXP 8
#define CAP   1280

typedef short short8 __attribute__((ext_vector_type(8)));
typedef float f32x4 __attribute__((ext_vector_type(4)));

__device__ __forceinline__ u16 bf16rne(float f) {
    u32 u = __float_as_uint(f);
    u32 r = u + 0x7FFFu + ((u >> 16) & 1u);
    return (u16)(r >> 16);
}
__device__ __forceinline__ float bf2f(u16 h) {
    return __uint_as_float(((u32)h) << 16);
}

#define GLDS(gp, lp) __builtin_amdgcn_global_load_lds( \
    (const __attribute__((address_space(1))) void*)(gp), \
    (__attribute__((address_space(3))) void*)(lp), 16, 0, 0)

// ---------------- Router: one wave per token ----------------
__global__ void router_kernel(const float* __restrict__ x,
                              const float* __restrict__ gw,
                              int* __restrict__ r_eidx,
                              float* __restrict__ r_w) {
    const int wave = threadIdx.x >> 6, lane = threadIdx.x & 63;
    const int t = blockIdx.x * 4 + wave;
    const float* xr = x + (size_t)t * DIM;
    float acc[8];
#pragma unroll
    for (int e = 0; e < 8; e++) acc[e] = 0.f;
#pragma unroll 4
    for (int i = 0; i < DIM / 64; i++) {
        int d = i * 64 + lane;
        float xv = xr[d];
        const float4* g = (const float4*)(gw + (size_t)d * 8);
        float4 g0 = g[0], g1 = g[1];
        acc[0] += xv * g0.x; acc[1] += xv * g0.y;
        acc[2] += xv * g0.z; acc[3] += xv * g0.w;
        acc[4] += xv * g1.x; acc[5] += xv * g1.y;
        acc[6] += xv * g1.z; acc[7] += xv * g1.w;
    }
#pragma unroll
    for (int e = 0; e < 8; e++) {
#pragma unroll
        for (int off = 32; off > 0; off >>= 1)
            acc[e] += __shfl_xor(acc[e], off, 64);
    }
    if (lane == 0) {
        int e0 = 0; float l0 = acc[0];
#pragma unroll
        for (int e = 1; e < 8; e++) if (acc[e] > l0) { l0 = acc[e]; e0 = e; }
        int e1 = -1; float l1 = -1e30f;
#pragma unroll
        for (int e = 0; e < 8; e++) if (e != e0 && acc[e] > l1) { l1 = acc[e]; e1 = e; }
        float z = __expf(l1 - l0);          // <= 1
        float inv = 1.f / (1.f + z);
        r_eidx[t] = e0; r_eidx[N_TOK + t] = e1;
        r_w[t] = inv;   r_w[N_TOK + t] = z * inv;
    }
}

// ---------------- Capacity assignment: single block, deterministic scan ------
__global__ void assign_kernel(const int* __restrict__ r_eidx,
                              int* __restrict__ assign_slot,
                              int* __restrict__ token_for_slot,
                              int* __restrict__ used) {
    const int tid = threadIdx.x;                 // 0..1023
    __shared__ int wtot[8][16];
    __shared__ int wbase[8][16];
    for (int i = tid; i < N_EXP * CAP; i += 1024) token_for_slot[i] = -1;

    int le[8], lr[8], cnt[8];
#pragma unroll
    for (int e = 0; e < 8; e++) cnt[e] = 0;
#pragma unroll
    for (int j = 0; j < 8; j++) {
        int e = r_eidx[tid * 8 + j];
        le[j] = e;
        int r = 0;
#pragma unroll
        for (int e2 = 0; e2 < 8; e2++)
            if (e == e2) { r = cnt[e2]; cnt[e2] = r + 1; }
        lr[j] = r;
    }
    const int lane = tid & 63, wv = tid >> 6;    // 16 waves
    int excl[8];
#pragma unroll
    for (int e = 0; e < 8; e++) {
        int v = cnt[e], inc = v;
#pragma unroll
        for (int off = 1; off < 64; off <<= 1) {
            int u = __shfl_up(inc, off, 64);
            if (lane >= off) inc += u;
        }
        excl[e] = inc - v;
        if (lane == 63) wtot[e][wv] = inc;
    }
    __syncthreads();
    if (tid < 8) {
        int s = 0;
        for (int w = 0; w < 16; w++) { wbase[tid][w] = s; s += wtot[tid][w]; }
        used[tid] = s < CAP ? s : CAP;
    }
    __syncthreads();
#pragma unroll
    for (int j = 0; j < 8; j++) {
        int i = tid * 8 + j;
        int e = le[j];
        int b = 0;
#pragma unroll
        for (int e2 = 0; e2 < 8; e2++)
            if (e == e2) b = wbase[e2][wv] + excl[e2];
        int rank = b + lr[j];
        int tok = i & (N_TOK - 1);
        if (rank < CAP) {
            assign_slot[i] = rank;
            token_for_slot[e * CAP + rank] = tok;
        } else {
            assign_slot[i] = -1;
        }
    }
}

// ---------------- Gather tokens into per-expert batches (bf16) ----------------
__global__ void gather_kernel(const float* __restrict__ x,
                              const int* __restrict__ token_for_slot,
                              u16* __restrict__ exp_batches) {
    const int s = blockIdx.x;
    const int tok = token_for_slot[s];
    const int d = threadIdx.x * 4;
    ushort4 o;
    if (tok >= 0) {
        float4 v = *(const float4*)(x + (size_t)tok * DIM + d);
        o = make_ushort4(bf16rne(v.x), bf16rne(v.y), bf16rne(v.z), bf16rne(v.w));
    } else {
        o = make_ushort4(0, 0, 0, 0);
    }
    *(ushort4*)(exp_batches + (size_t)s * DIM + d) = o;
}

// ---------------- Weight transpose+convert: f32 [R][C] -> bf16 [C][R] --------
__global__ __launch_bounds__(256) void transpose_cvt(
    const float* __restrict__ in, u16* __restrict__ out, int R, int C) {
    __shared__ float t[64][65];
    const int ez = blockIdx.z;
    in  += (size_t)ez * R * C;
    out += (size_t)ez * R * C;
    const int row0 = blockIdx.y * 64, col0 = blockIdx.x * 64;
    const int tid = threadIdx.x;
    {
        const int r = tid >> 2, cq = (tid & 3) * 16;
        const float* p = in + (size_t)(row0 + r) * C + col0 + cq;
        float4 v0 = ((const float4*)p)[0];
        float4 v1 = ((const float4*)p)[1];
        float4 v2 = ((const float4*)p)[2];
        float4 v3 = ((const float4*)p)[3];
        float tmp[16] = {v0.x, v0.y, v0.z, v0.w, v1.x, v1.y, v1.z, v1.w,
                         v2.x, v2.y, v2.z, v2.w, v3.x, v3.y, v3.z, v3.w};
#pragma unroll
        for (int j = 0; j < 16; j++) t[r][cq + j] = tmp[j];
    }
    __syncthreads();
    {
        const int oc = tid >> 2, h4 = (tid & 3) * 16;
        u16 o[16];
#pragma unroll
        for (int i = 0; i < 16; i++) o[i] = bf16rne(t[h4 + i][oc]);
        u16* q = out + (size_t)(col0 + oc) * R + row0 + h4;
        *(uint4*)q = *(const uint4*)&o[0];
        *(uint4*)(q + 8) = *(const uint4*)&o[8];
    }
}

// ---------------- MFMA GEMM (16x16x32, 0-conflict): C = epi(A @ Bt^T + bias) --
// A: [M,K] bf16 row-major.  Bt: [N,K] bf16 row-major (pre-transposed weights).
// LDS [128][64] bf16 unpadded; k-chunk XOR-swizzled by row&7 in the GLOBAL
// address (DMA-legal; permutation stays inside one 128B row).
// Early-exit: blocks whose 128-row tile is entirely >= used[e] skip all work
// (those slots are never read by combine).
template <bool DO_GELU>
__global__ __launch_bounds__(256, 2) void moe_gemm(
    const u16* __restrict__ A, const u16* __restrict__ Bt,
    const float* __restrict__ bias, u16* __restrict__ C,
    const int* __restrict__ used, int M, int N, int K) {
    __shared__ __align__(16) u16 As[128 * 64];
    __shared__ __align__(16) u16 Bs[128 * 64];

    const int e = blockIdx.z;
    const int row0 = blockIdx.y * 128, col0 = blockIdx.x * 128;
    if (row0 >= used[e]) return;    // uniform per block

    A    += (size_t)e * M * K;
    Bt   += (size_t)e * N * K;
    bias += (size_t)e * N;
    C    += (size_t)e * M * N;

    const int tid = threadIdx.x;
    const int lane = tid & 63, wave = tid >> 6;
    const int wr = (wave >> 1) * 64, wc = (wave & 1) * 64;

    f32x4 acc[4][4];
#pragma unroll
    for (int i = 0; i < 4; i++)
#pragma unroll
        for (int j = 0; j < 4; j++) acc[i][j] = (f32x4){0.f, 0.f, 0.f, 0.f};

    // staging: chunk = wave*4+i covers LDS bytes chunk*1024 + lane*16
    const int srow = lane >> 3;
    const int swz = ((lane & 7) ^ srow) * 8;     // XOR k-swizzle by row&7
    const u16* Ab = A + (size_t)(row0 + wave * 32 + srow) * K + swz;
    const u16* Bb = Bt + (size_t)(col0 + wave * 32 + srow) * K + swz;
    u16* Asw = As + (wave * 4) * 512;
    u16* Bsw = Bs + (wave * 4) * 512;

    const int rrd = lane & 15, qrd = lane >> 4;
    const int sw = rrd & 7;                       // frag-read swizzle key

    for (int kt = 0; kt < K; kt += 64) {
#pragma unroll
        for (int i = 0; i < 4; i++)
            GLDS(Ab + (size_t)(i * 8) * K + kt, Asw + i * 512);
#pragma unroll
        for (int i = 0; i < 4; i++)
            GLDS(Bb + (size_t)(i * 8) * K + kt, Bsw + i * 512);
        __syncthreads();
#pragma unroll
        for (int ks = 0; ks < 2; ks++) {
            const int kc = ks * 4 + qrd;          // logical k-chunk 0..7
            const int krd = (kc ^ sw) * 8;        // swizzled element offset
            short8 af[4], bfr[4];
#pragma unroll
            for (int i = 0; i < 4; i++)
                af[i] = *(const short8*)(As + (wr + i * 16 + rrd) * 64 + krd);
#pragma unroll
            for (int j = 0; j < 4; j++)
                bfr[j] = *(const short8*)(Bs + (wc + j * 16 + rrd) * 64 + krd);
#pragma unroll
            for (int i = 0; i < 4; i++)
#pragma unroll
                for (int j = 0; j < 4; j++)
                    acc[i][j] = __builtin_amdgcn_mfma_f32_16x16x32_bf16(
                        af[i], bfr[j], acc[i][j], 0, 0, 0);
        }
        __syncthreads();
    }
    // ---- epilogue: bias (+gelu, tanh form) -> bf16 ----
    const int cr = (lane >> 4) * 4;
    const int cc = lane & 15;
#pragma unroll
    for (int j = 0; j < 4; j++) {
        const int col = col0 + wc + j * 16 + cc;
        const float bv = bias[col];
#pragma unroll
        for (int i = 0; i < 4; i++) {
#pragma unroll
            for (int r = 0; r < 4; r++) {
                int row = row0 + wr + i * 16 + cr + r;
                float v = acc[i][j][r] + bv;
                if (DO_GELU) {
                    float u = 0.7978845608f * v * (1.f + 0.044715f * v * v);
                    v = v / (1.f + __expf(-2.f * u));
                }
                C[(size_t)row * N + col] = bf16rne(v);
            }
        }
    }
}

// ---------------- Combine: out = w0*expOut[e0,s0] + w1*expOut[e1,s1] ----------
__global__ void combine_kernel(const int* __restrict__ r_eidx,
                               const float* __restrict__ r_w,
                               const int* __restrict__ assign_slot,
                               const u16* __restrict__ exp_out,
                               float* __restrict__ out) {
    const int t = blockIdx.x;
    const int d = threadIdx.x * 4;
    const int e0 = r_eidx[t], e1 = r_eidx[N_TOK + t];
    const float w0 = r_w[t], w1 = r_w[N_TOK + t];
    const int s0 = assign_slot[t], s1 = assign_slot[N_TOK + t];
    float v0 = 0.f, v1 = 0.f, v2 = 0.f, v3 = 0.f;
    if (s0 >= 0) {
        const u16* p = exp_out + ((size_t)e0 * CAP + s0) * DIM + d;
        ushort4 q = *(const ushort4*)p;
        v0 += w0 * bf2f(q.x); v1 += w0 * bf2f(q.y);
        v2 += w0 * bf2f(q.z); v3 += w0 * bf2f(q.w);
    }
    if (s1 >= 0) {
        const u16* p = exp_out + ((size_t)e1 * CAP + s1) * DIM + d;
        ushort4 q = *(const ushort4*)p;
        v0 += w1 * bf2f(q.x); v1 += w1 * bf2f(q.y);
        v2 += w1 * bf2f(q.z); v3 += w1 * bf2f(q.w);
    }
    float4 o; o.x = v0; o.y = v1; o.z = v2; o.w = v3;
    *(float4*)(out + (size_t)t * DIM + d) = o;
}

// ---------------- Launch ----------------
extern "C" void kernel_launch(void* const* d_in, const int* in_sizes, int n_in,
                              void* d_out, int out_size, void* d_ws, size_t ws_size,
                              hipStream_t stream) {
    const float* x         = (const float*)d_in[0];
    const float* gate_w    = (const float*)d_in[1];
    const float* c_fc      = (const float*)d_in[2];
    const float* fc_bias   = (const float*)d_in[3];
    const float* c_proj    = (const float*)d_in[4];
    const float* proj_bias = (const float*)d_in[5];
    float* out = (float*)d_out;
    char* ws = (char*)d_ws;

    // workspace layout (bytes)
    int*   r_eidx         = (int*)(ws + 0);              //  32 KB
    float* r_w            = (float*)(ws + 32768);        //  32 KB
    int*   assign_slot    = (int*)(ws + 65536);          //  32 KB
    int*   token_for_slot = (int*)(ws + 98304);          //  40 KB
    int*   used           = (int*)(ws + 139264);         //  32 B (pad to 24 KB)
    u16*   exp_batches    = (u16*)(ws + 163840);         //  20.97 MB [10240,1024]
    u16*   exp_out        = exp_batches;                 //  aliased (dead after GEMM1)
    u16*   h              = (u16*)(ws + 21135360);       //  83.9  MB [10240,4096]
    u16*   Bt             = (u16*)(ws + 105021440);      //  64 MB (Bt1 then Bt2)
    // total: 172,130,304 bytes (~164 MB)

    router_kernel<<<N_TOK / 4, 256, 0, stream>>>(x, gate_w, r_eidx, r_w);
    assign_kernel<<<1, 1024, 0, stream>>>(r_eidx, assign_slot, token_for_slot, used);
    gather_kernel<<<N_EXP * CAP, 256, 0, stream>>>(x, token_for_slot, exp_batches);

    // Bt1 = c_fc^T per expert: [D,H] -> [H,D]
    transpose_cvt<<<dim3(HID / 64, DIM / 64, N_EXP), 256, 0, stream>>>(
        c_fc, Bt, DIM, HID);
    moe_gemm<true><<<dim3(HID / 128, CAP / 128, N_EXP), 256, 0, stream>>>(
        exp_batches, Bt, fc_bias, h, used, CAP, HID, DIM);

    // Bt2 = c_proj^T per expert: [H,D] -> [D,H]  (aliases Bt1, now dead)
    transpose_cvt<<<dim3(DIM / 64, HID / 64, N_EXP), 256, 0, stream>>>(
        c_proj, Bt, HID, DIM);
    moe_gemm<false><<<dim3(DIM / 128, CAP / 128, N_EXP), 256, 0, stream>>>(
        h, Bt, proj_bias, exp_out, used, CAP, DIM, HID);

    combine_kernel<<<N_TOK, 256, 0, stream>>>(r_eidx, r_w, assign_slot, exp_out, out);
}